// Round 6
// baseline (336.350 us; speedup 1.0000x reference)
//
#include <hip/hip_runtime.h>

// Problem constants (from reference)
constexpr int S  = 4096;   // N_SAMPLES
constexpr int W  = 16;     // N_WIDTH
constexpr int NN = 193;    // N_NODES
constexpr int DD = 2;      // NDIM_IN
constexpr int SW = S * W;                      // 65536
constexpr int PHI_OFF = 3 * SW;                // after t, dt, ddt (floats)
constexpr int PHI_SZ  = SW * NN * DD;          // 25,296,896 floats per tensor
constexpr long DX_OFF = (long)PHI_OFF + 3L * PHI_SZ;  // 76,087,296
constexpr int ROW_F = NN * DD;                 // 386 floats per (i,k) row

// Cubic Lagrange basis at nodes {-1,-1/3,1/3,1}: values (a=0), d/dx (a=1),
// d2/dx2 (a=2) — derivative scales 1/dx=2^7, 1/dx^2=2^14 exact.
__device__ __forceinline__ void basis_a(int a, float xvd, int& nl, float c[4]) {
    float xs = 192.0f * xvd;
    float fe = floorf(xs * (1.0f / 3.0f));
    fe = fminf(fmaxf(fe, 0.0f), 63.0f);
    nl = (int)(fe * 3.0f);
    float xr = 2.0f * (xs - (float)nl) * (1.0f / 3.0f) - 1.0f;

    const float k0 = 0.5625f;    // 9/16
    const float k1 = 1.6875f;    // 27/16
    float x2  = xr * xr;
    float x2m = x2 - (1.0f / 9.0f);
    float xp1 = xr + 1.0f;
    float xm1 = xr - 1.0f;

    if (a == 0) {
        c[0] = -k0 * x2m * xm1;
        c[1] =  k1 * xp1 * (xr - (1.0f / 3.0f)) * xm1;
        c[2] = -k1 * xp1 * (xr + (1.0f / 3.0f)) * xm1;
        c[3] =  k0 * xp1 * x2m;
    } else if (a == 1) {
        const float s1 = 128.0f;
        c[0] = -k0 * (3.0f * x2 - 2.0f * xr - (1.0f / 9.0f)) * s1;
        c[1] =  k1 * (3.0f * x2 - (2.0f / 3.0f) * xr - 1.0f) * s1;
        c[2] = -k1 * (3.0f * x2 + (2.0f / 3.0f) * xr - 1.0f) * s1;
        c[3] =  k0 * (3.0f * x2 + 2.0f * xr - (1.0f / 9.0f)) * s1;
    } else {
        const float s2 = 16384.0f;
        c[0] = -k0 * (6.0f * xr - 2.0f) * s2;
        c[1] =  k1 * (6.0f * xr - (2.0f / 3.0f)) * s2;
        c[2] = -k1 * (6.0f * xr + (2.0f / 3.0f)) * s2;
        c[3] =  k0 * (6.0f * xr + 2.0f) * s2;
    }
}

// Runs AFTER the memset zeroed the phi region. One block per sample i.
// tid in [0,384): a = tid>>7 (wave-uniform), r = tid&127: k=r>>3, d=(r>>2)&1,
// p=r&3 -> each thread writes exactly one nonzero basis value.
__global__ __launch_bounds__(384)
void kan_scatter(const float* __restrict__ x,
                 const float* __restrict__ w,
                 float* __restrict__ out) {
    const int i   = blockIdx.x;
    const int tid = threadIdx.x;

    {
        int a = tid >> 7;
        int r = tid & 127;
        int k = r >> 3;
        int d = (r >> 2) & 1;
        int p = r & 3;
        float xv = x[2 * i + d];
        int nl; float c[4];
        basis_a(a, xv, nl, c);
        float v = (p == 0) ? c[0] : (p == 1) ? c[1] : (p == 2) ? c[2] : c[3];
        out[(size_t)PHI_OFF + (size_t)a * PHI_SZ
            + (size_t)i * (W * ROW_F) + k * ROW_F + (nl + p) * 2 + d] = v;
    }

    // t/dt/ddt: 48 threads (16 k x 3 tensors), 8-term dot products.
    if (tid < 48) {
        int a2 = tid % 3;
        int kk = tid / 3;
        int nl0, nl1; float c0[4], c1[4];
        basis_a(a2, x[2 * i],     nl0, c0);
        basis_a(a2, x[2 * i + 1], nl1, c1);
        const float* wk = w + kk * ROW_F;
        float s = 0.0f;
#pragma unroll
        for (int p = 0; p < 4; ++p) {
            s += wk[(nl0 + p) * 2 + 0] * c0[p];
            s += wk[(nl1 + p) * 2 + 1] * c1[p];
        }
        out[a2 * SW + i * W + kk] = s;
    }

    if (i == 0 && tid == 0)
        out[DX_OFF] = 0.0078125f;   // delta_x = 0.5*3*(1-0)/192
}

extern "C" void kernel_launch(void* const* d_in, const int* in_sizes, int n_in,
                              void* d_out, int out_size, void* d_ws, size_t ws_size,
                              hipStream_t stream) {
    const float* x = (const float*)d_in[0];   // (4096, 2) fp32
    const float* w = (const float*)d_in[1];   // (16, 193, 2) fp32
    float* out = (float*)d_out;

    // Zero the entire phi/dphi/ddphi block (contiguous, 303,562,752 bytes)
    // with the driver's fill path (~6.2 TB/s measured on this device).
    hipMemsetAsync(out + PHI_OFF, 0, 3L * PHI_SZ * sizeof(float), stream);

    // Then scatter the 1.57M nonzeros + the t/dt/ddt heads + delta_x.
    kan_scatter<<<S, 384, 0, stream>>>(x, w, out);
}